// Round 3
// baseline (334.074 us; speedup 1.0000x reference)
//
#include <hip/hip_runtime.h>
#include <stdint.h>
#include <stddef.h>

typedef __attribute__((ext_vector_type(4))) float f32x4;
typedef __attribute__((ext_vector_type(16))) float f32x16;
typedef __attribute__((ext_vector_type(8))) short bf16x8;

#define BMN 256      // block tile M = N
#define BK  64       // K per K-tile
#define NTHREADS 512

// Round-to-nearest-even fp32 mantissa to 10 bits (shift = 23-10 = 13).
__device__ __forceinline__ float round_m10(float x) {
    int b = __float_as_int(x);
    int rb = ((b >> 13) & 1) + 0x0FFF;
    b = (b + rb) & (int)0xFFFFE000;
    return __int_as_float(b);
}

__device__ __forceinline__ unsigned short f32_to_bf16(float x) {
    unsigned int u = __float_as_uint(x);
    u += 0x7FFFu + ((u >> 16) & 1u);
    return (unsigned short)(u >> 16);
}

// fp32 -> bf16 with the 3-bit bank swizzle BAKED IN: the 16B chunk at logical
// (row, c) is stored at (row, (c & ~7) | ((c&7) ^ (row&7))). Permutation acts
// within each 128B row-window; all tile offsets are 128B-aligned, so LDS
// staging reads LINEARLY and inherits the swizzle (rule #21).
__global__ void convert_f32_bf16_swz(const float* __restrict__ in,
                                     unsigned short* __restrict__ out,
                                     long nchunks, int cpr /* chunks per row = K/8 */) {
    long g = (long)blockIdx.x * blockDim.x + threadIdx.x;
    const long stride = (long)gridDim.x * blockDim.x;
    for (; g < nchunks; g += stride) {
        const long row = g / cpr;
        const int c = (int)(g - row * cpr);
        const float* p = in + g * 8;
        f32x4 v0 = *(const f32x4*)p;
        f32x4 v1 = *(const f32x4*)(p + 4);
        bf16x8 o;
        o[0] = (short)f32_to_bf16(v0[0]); o[1] = (short)f32_to_bf16(v0[1]);
        o[2] = (short)f32_to_bf16(v0[2]); o[3] = (short)f32_to_bf16(v0[3]);
        o[4] = (short)f32_to_bf16(v1[0]); o[5] = (short)f32_to_bf16(v1[1]);
        o[6] = (short)f32_to_bf16(v1[2]); o[7] = (short)f32_to_bf16(v1[3]);
        const int cdst = (c & ~7) | ((c & 7) ^ ((int)row & 7));
        *(bf16x8*)(out + (row * (long)cpr + cdst) * 8) = o;
    }
}

__device__ __forceinline__ void gload_lds16(const unsigned short* g, unsigned short* l) {
    __builtin_amdgcn_global_load_lds(
        (const __attribute__((address_space(1))) void*)g,
        (__attribute__((address_space(3))) void*)l, 16, 0, 0);
}

// Stage one 128x64 bf16 half-tile (16 KB): 2 global_load_lds x16 per thread.
// Source is PRE-SWIZZLED, so global read AND LDS dest are perfectly linear.
__device__ __forceinline__ void stage_half(const unsigned short* __restrict__ G,
                                           unsigned short* lds,
                                           int grow0, int gcol, int K, int tid) {
    const int wave = tid >> 6;
#pragma unroll
    for (int p = 0; p < 2; ++p) {
        const int s = tid + p * NTHREADS;            // 16B chunk 0..1023
        const int row = s >> 3;                      // 0..127
        const unsigned short* g = G + (size_t)(grow0 + row) * K + gcol + (s & 7) * 8;
        unsigned short* l = lds + (size_t)(wave * 64 + p * NTHREADS) * 8;
        gload_lds16(g, l);
    }
}

// R16: 32x32x16 MFMA (2495 TF ubench vs ~2100 for 16x16x32) with an AIRTIGHT
// phase discipline (R15's single-barrier tail-read variant raced post-timing):
//   phase = [STG? | vmcnt? | bar1(publish, P4/P8 only) | MFMA ∥ tail-reads |
//            sched_barrier | lgkmcnt(0) drain | bar2]
// Every wave's tail reads are fully SERVICED before any wave passes bar2, and
// every restage issues after that bar2 -> the WAR window is structurally zero
// (not latency-margin-dependent). sched_barrier(0) pins stop the compiler
// sinking/hoisting plain ds_reads across barriers (loads are not
// side-effecting; naked asm waitcnts don't fence them).
// Ring: A,B frags both read 1 phase ahead (a0/a1, b0/b1). Stages: buf0<-t+2
// spread P4..P7 (2 loads each), buf1<-t+3 at P8 (8 loads). Publishes:
// vmcnt(2)@P4 (drains P8prev's 8 = buf1(t+1)), vmcnt(8)@P8 (drains P4..P7's
// 8 = buf0(t+2)). All counted; never drained to 0 in the loop.
__global__ __launch_bounds__(NTHREADS, 2)
void gemm8p(const unsigned short* __restrict__ Abf, const unsigned short* __restrict__ Bbf,
            const float* __restrict__ bias, float* __restrict__ out,
            int M, int N, int K) {
    // [buf][half][128 rows][64 k] bf16 (swizzled layout) — 128 KB total
    __shared__ unsigned short sA[2][2][128 * 64];
    __shared__ unsigned short sB[2][2][128 * 64];

    const int tid  = threadIdx.x;
    const int lane = tid & 63;
    const int wave = tid >> 6;
    const int wm = wave >> 2;          // 0..1 : A-half / wave's 128-row band
    const int wn = wave & 3;           // 0..3 : 64-col band (B-half = wn>>1)
    const int li = lane & 31;          // row/col within a 32-block
    const int hi = lane >> 5;          // k-half of the 16-k step
    const int NT = K / BK;

    // Bijective XCD-chunk swizzle (T1); grid is (N/256, M/256).
    const int gx = gridDim.x;
    const int nwg = gx * gridDim.y;
    int lin = blockIdx.y * gx + blockIdx.x;
    if ((nwg & 7) == 0) lin = (lin & 7) * (nwg >> 3) + (lin >> 3);
    const int bm0 = (lin / gx) * BMN;
    const int bn0 = (lin % gx) * BMN;

    // Fragment-read offsets. kstep s covers k = s*16 + hi*8 + 0..7, i.e.
    // logical 16B-chunk 2s+hi; baked swizzle -> phys = (2s+hi) ^ (row&7),
    // row&7 = li&7 (block bases are multiples of 32).
    const int r7  = li & 7;
    const int kc0 = ((0 + hi) ^ r7) * 8;
    const int kc1 = ((2 + hi) ^ r7) * 8;
    const int kc2 = ((4 + hi) ^ r7) * 8;
    const int kc3 = ((6 + hi) ^ r7) * 8;
    const int Arow = li * 64;
    const int Brow = ((wn & 1) * 64 + li) * 64;

    const unsigned short* Ab0 = &sA[0][wm][0];
    const unsigned short* Ab1 = &sA[1][wm][0];
    const unsigned short* Bb0 = &sB[0][wn >> 1][0];
    const unsigned short* Bb1 = &sB[1][wn >> 1][0];

    // 8 accumulator tiles of 32x32: [b(4 row-blocks)][cb(2 col-blocks)]
    f32x16 acc[8];
    {
        f32x16 z;
#pragma unroll
        for (int e = 0; e < 16; ++e) z[e] = 0.0f;
#pragma unroll
        for (int i = 0; i < 8; ++i) acc[i] = z;
    }

    // 1-phase-ahead ping-pong operand sets.
    bf16x8 a0[4], a1[4], b0[2], b1[2];

#define RD_A32(dst, base, kc) { const unsigned short* _pa = (base); \
    _Pragma("unroll") for (int b = 0; b < 4; ++b) \
        dst[b] = *(const bf16x8*)&_pa[b * 2048 + Arow + (kc)]; }
#define RD_B32(dst, base, kc) { const unsigned short* _pb = (base); \
    _Pragma("unroll") for (int cb = 0; cb < 2; ++cb) \
        dst[cb] = *(const bf16x8*)&_pb[cb * 2048 + Brow + (kc)]; }

#define MFMA8(aU, bU) \
    __builtin_amdgcn_s_setprio(1); \
    _Pragma("unroll") for (int b = 0; b < 4; ++b) \
    _Pragma("unroll") for (int cb = 0; cb < 2; ++cb) \
        acc[b * 2 + cb] = __builtin_amdgcn_mfma_f32_32x32x16_bf16(aU[b], bU[cb], acc[b * 2 + cb], 0, 0, 0); \
    __builtin_amdgcn_s_setprio(0);

// Plain phase: optional stage at head; MFMA with tail reads interleaved by
// the scheduler; pinned drain of OWN reads; bar2 = region boundary.
#define PH_PLAIN(aU, bU, RDS, STG) \
    __builtin_amdgcn_sched_barrier(0); \
    STG \
    MFMA8(aU, bU) \
    RDS \
    __builtin_amdgcn_sched_barrier(0); \
    asm volatile("s_waitcnt lgkmcnt(0)"); \
    __builtin_amdgcn_s_barrier();

// Publish phase: stage; counted vmcnt; bar1 publishes the freshly-landed
// buffer; pinned so the tail reads of that buffer cannot hoist above bar1.
#define PH_PUB(aU, bU, RDS, STG, VMW) \
    __builtin_amdgcn_sched_barrier(0); \
    STG \
    VMW \
    __builtin_amdgcn_sched_barrier(0); \
    __builtin_amdgcn_s_barrier(); \
    __builtin_amdgcn_sched_barrier(0); \
    MFMA8(aU, bU) \
    RDS \
    __builtin_amdgcn_sched_barrier(0); \
    asm volatile("s_waitcnt lgkmcnt(0)"); \
    __builtin_amdgcn_s_barrier();

    // ---- prologue: buf0 <- tile0 (8 loads) FIRST, then buf1 <- tile1 (8).
    stage_half(Abf, &sA[0][0][0], bm0,       0,  K, tid);
    stage_half(Abf, &sA[0][1][0], bm0 + 128, 0,  K, tid);
    stage_half(Bbf, &sB[0][0][0], bn0,       0,  K, tid);
    stage_half(Bbf, &sB[0][1][0], bn0 + 128, 0,  K, tid);
    stage_half(Abf, &sA[1][0][0], bm0,       BK, K, tid);
    stage_half(Abf, &sA[1][1][0], bm0 + 128, BK, K, tid);
    stage_half(Bbf, &sB[1][0][0], bn0,       BK, K, tid);
    stage_half(Bbf, &sB[1][1][0], bn0 + 128, BK, K, tid);
    asm volatile("s_waitcnt vmcnt(8)");      // drain buf0's 8; buf1's 8 in flight
    __builtin_amdgcn_s_barrier();
    __builtin_amdgcn_sched_barrier(0);
    RD_A32(a0, Ab0, kc0)
    RD_B32(b0, Bb0, kc0)

    // ---- main loop: 2 K-tiles per iteration (buf0 = t, buf1 = t+1).
    for (int t = 0; t < NT; t += 2) {
        int u2 = t + 2; if (u2 >= NT) u2 -= NT;   // wrap stages = harmless dummies
        int u3 = t + 3; if (u3 >= NT) u3 -= NT;
        const int k2 = u2 * BK, k3 = u3 * BK;

        // P1: t.s0; tail reads t.s1
        PH_PLAIN(a0, b0,
                 RD_A32(a1, Ab0, kc1) RD_B32(b1, Bb0, kc1), )

        // P2: t.s1; tail t.s2
        PH_PLAIN(a1, b1,
                 RD_A32(a0, Ab0, kc2) RD_B32(b0, Bb0, kc2), )

        // P3: t.s2; tail t.s3 (last buf0 reads; drained before bar2-P3)
        PH_PLAIN(a0, b0,
                 RD_A32(a1, Ab0, kc3) RD_B32(b1, Bb0, kc3), )

        // P4: t.s3; stage buf0-A-h0 (t+2); vmcnt(2) + bar1 publish buf1(t+1);
        //     tail reads t+1.s0 (pinned below bar1)
        PH_PUB(a1, b1,
               RD_A32(a0, Ab1, kc0) RD_B32(b0, Bb1, kc0),
               stage_half(Abf, &sA[0][0][0], bm0, k2, K, tid);,
               asm volatile("s_waitcnt vmcnt(2)");)

        // P5: t+1.s0; stage buf0-A-h1; tail t+1.s1
        PH_PLAIN(a0, b0,
                 RD_A32(a1, Ab1, kc1) RD_B32(b1, Bb1, kc1),
                 stage_half(Abf, &sA[0][1][0], bm0 + 128, k2, K, tid);)

        // P6: t+1.s1; stage buf0-B-h0; tail t+1.s2
        PH_PLAIN(a1, b1,
                 RD_A32(a0, Ab1, kc2) RD_B32(b0, Bb1, kc2),
                 stage_half(Bbf, &sB[0][0][0], bn0, k2, K, tid);)

        // P7: t+1.s2; stage buf0-B-h1; tail t+1.s3 (last buf1 reads)
        PH_PLAIN(a0, b0,
                 RD_A32(a1, Ab1, kc3) RD_B32(b1, Bb1, kc3),
                 stage_half(Bbf, &sB[0][1][0], bn0 + 128, k2, K, tid);)

        // P8: t+1.s3; stage buf1 (t+3, 8 loads); vmcnt(8) + bar1 publish
        //     buf0(t+2); tail reads t+2.s0 (pinned below bar1)
        PH_PUB(a1, b1,
               RD_A32(a0, Ab0, kc0) RD_B32(b0, Bb0, kc0),
               stage_half(Abf, &sA[1][0][0], bm0, k3, K, tid);
               stage_half(Abf, &sA[1][1][0], bm0 + 128, k3, K, tid);
               stage_half(Bbf, &sB[1][0][0], bn0, k3, K, tid);
               stage_half(Bbf, &sB[1][1][0], bn0 + 128, k3, K, tid);,
               asm volatile("s_waitcnt vmcnt(8)");)
    }

    asm volatile("s_waitcnt vmcnt(0) lgkmcnt(0)" ::: "memory");  // drain

    // ---- epilogue: + bias, final mantissa round, store fp32.
    // 32x32 C/D layout (verified m74/m101): col = lane&31,
    // row = (e&3) + 8*(e>>2) + 4*(lane>>5).
#pragma unroll
    for (int b = 0; b < 4; ++b) {
        const int row0 = bm0 + wm * 128 + b * 32 + 4 * hi;
#pragma unroll
        for (int cb = 0; cb < 2; ++cb) {
            const int col = bn0 + wn * 64 + cb * 32 + li;
            const float bv = bias[col];
#pragma unroll
            for (int g = 0; g < 4; ++g)
#pragma unroll
                for (int r = 0; r < 4; ++r)
                    out[(size_t)(row0 + g * 8 + r) * N + col] =
                        round_m10(acc[b * 2 + cb][g * 4 + r] + bv);
        }
    }
#undef RD_A32
#undef RD_B32
#undef MFMA8
#undef PH_PLAIN
#undef PH_PUB
}

// Fallback: fused fp32->bf16 128^2 kernel (only for shapes the main path rejects).
__global__ __launch_bounds__(256)
void gemm_fallback(const float* __restrict__ A, const float* __restrict__ B,
                   const float* __restrict__ bias, float* __restrict__ out,
                   int M, int N, int K) {
    __shared__ unsigned short lds_a[128 * 64];
    __shared__ unsigned short lds_b[128 * 64];
    const int tid = threadIdx.x, lane = tid & 63, wave = tid >> 6;
    const int wm = wave >> 1, wn = wave & 1;
    const int bm0 = blockIdx.y * 128, bn0 = blockIdx.x * 128;
    const int lrow = lane & 15, lkg = lane >> 4;
    f32x4 acc[4][4];
    const f32x4 zero = {0.f, 0.f, 0.f, 0.f};
#pragma unroll
    for (int i = 0; i < 4; ++i)
#pragma unroll
        for (int j = 0; j < 4; ++j) acc[i][j] = zero;
    for (int kb = 0; kb < K / 64; ++kb) {
        const int kt = kb * 64;
        const int r0 = tid >> 4, c0 = (tid & 15) << 2;
#pragma unroll
        for (int p = 0; p < 8; ++p) {
            const int r = p * 16 + r0;
            f32x4 va = *(const f32x4*)(A + (size_t)(bm0 + r) * K + kt + c0);
            f32x4 vb = *(const f32x4*)(B + (size_t)(bn0 + r) * K + kt + c0);
            ushort4 ua, ub;
            ua.x = f32_to_bf16(va[0]); ua.y = f32_to_bf16(va[1]);
            ua.z = f32_to_bf16(va[2]); ua.w = f32_to_bf16(va[3]);
            ub.x = f32_to_bf16(vb[0]); ub.y = f32_to_bf16(vb[1]);
            ub.z = f32_to_bf16(vb[2]); ub.w = f32_to_bf16(vb[3]);
            *(ushort4*)(&lds_a[r * 64 + c0]) = ua;
            *(ushort4*)(&lds_b[r * 64 + c0]) = ub;
        }
        __syncthreads();
#pragma unroll
        for (int kk = 0; kk < 64; kk += 32) {
            bf16x8 af[4], bfr[4];
#pragma unroll
            for (int i = 0; i < 4; ++i)
                af[i] = *(const bf16x8*)(&lds_a[(wm * 64 + i * 16 + lrow) * 64 + kk + lkg * 8]);
#pragma unroll
            for (int j = 0; j < 4; ++j)
                bfr[j] = *(const bf16x8*)(&lds_b[(wn * 64 + j * 16 + lrow) * 64 + kk + lkg * 8]);
#pragma unroll
            for (int i = 0; i < 4; ++i)
#pragma unroll
                for (int j = 0; j < 4; ++j)
                    acc[i][j] = __builtin_amdgcn_mfma_f32_16x16x32_bf16(af[i], bfr[j], acc[i][j], 0, 0, 0);
        }
        __syncthreads();
    }
#pragma unroll
    for (int i = 0; i < 4; ++i) {
        const int row0 = bm0 + wm * 64 + i * 16 + lkg * 4;
#pragma unroll
        for (int j = 0; j < 4; ++j) {
            const int col = bn0 + wn * 64 + j * 16 + lrow;
            const float bv = bias[col];
#pragma unroll
            for (int r = 0; r < 4; ++r)
                out[(size_t)(row0 + r) * N + col] = round_m10(acc[i][j][r] + bv);
        }
    }
}

extern "C" void kernel_launch(void* const* d_in, const int* in_sizes, int n_in,
                              void* d_out, int out_size, void* d_ws, size_t ws_size,
                              hipStream_t stream) {
    const float* x    = (const float*)d_in[0];   // [M, K]
    const float* w    = (const float*)d_in[1];   // [N, K]
    const float* bias = (const float*)d_in[2];   // [N]
    float* out = (float*)d_out;                  // [M, N]

    const int N = in_sizes[2];
    const int K = in_sizes[1] / N;
    const int M = in_sizes[0] / K;

    const size_t nx = (size_t)M * K;
    const size_t nw = (size_t)N * K;
    const size_t need = (nx + nw) * sizeof(unsigned short);
    const int NT = K / BK;

    if (ws_size >= need && (M % BMN) == 0 && (N % BMN) == 0 && (K % BK) == 0 &&
        NT >= 4 && (NT % 2) == 0) {
        unsigned short* xb = (unsigned short*)d_ws;
        unsigned short* wb = xb + nx;
        const int cpr = K / 8;
        convert_f32_bf16_swz<<<2048, 256, 0, stream>>>(x, xb, (long)(nx / 8), cpr);
        convert_f32_bf16_swz<<<2048, 256, 0, stream>>>(w, wb, (long)(nw / 8), cpr);
        dim3 grid(N / BMN, M / BMN);
        gemm8p<<<grid, NTHREADS, 0, stream>>>(xb, wb, bias, out, M, N, K);
    } else {
        dim3 grid(N / 128, M / 128);
        gemm_fallback<<<grid, 256, 0, stream>>>(x, w, bias, out, M, N, K);
    }
}

// Round 4
// 329.999 us; speedup vs baseline: 1.0123x; 1.0123x over previous
//
#include <hip/hip_runtime.h>
#include <stdint.h>
#include <stddef.h>

typedef __attribute__((ext_vector_type(4))) float f32x4;
typedef __attribute__((ext_vector_type(16))) float f32x16;
typedef __attribute__((ext_vector_type(8))) short bf16x8;

#define BMN 256      // block tile M = N
#define BK  64       // K per K-tile
#define NTHREADS 512

// Round-to-nearest-even fp32 mantissa to 10 bits (shift = 23-10 = 13).
__device__ __forceinline__ float round_m10(float x) {
    int b = __float_as_int(x);
    int rb = ((b >> 13) & 1) + 0x0FFF;
    b = (b + rb) & (int)0xFFFFE000;
    return __int_as_float(b);
}

__device__ __forceinline__ unsigned short f32_to_bf16(float x) {
    unsigned int u = __float_as_uint(x);
    u += 0x7FFFu + ((u >> 16) & 1u);
    return (unsigned short)(u >> 16);
}

// fp32 -> bf16 with the 3-bit bank swizzle BAKED IN: the 16B chunk at logical
// (row, c) is stored at (row, (c & ~7) | ((c&7) ^ (row&7))). Permutation acts
// within each 128B row-window; all tile offsets are 128B-aligned, so LDS
// staging reads LINEARLY and inherits the swizzle (rule #21).
__global__ void convert_f32_bf16_swz(const float* __restrict__ in,
                                     unsigned short* __restrict__ out,
                                     long nchunks, int cpr /* chunks per row = K/8 */) {
    long g = (long)blockIdx.x * blockDim.x + threadIdx.x;
    const long stride = (long)gridDim.x * blockDim.x;
    for (; g < nchunks; g += stride) {
        const long row = g / cpr;
        const int c = (int)(g - row * cpr);
        const float* p = in + g * 8;
        f32x4 v0 = *(const f32x4*)p;
        f32x4 v1 = *(const f32x4*)(p + 4);
        bf16x8 o;
        o[0] = (short)f32_to_bf16(v0[0]); o[1] = (short)f32_to_bf16(v0[1]);
        o[2] = (short)f32_to_bf16(v0[2]); o[3] = (short)f32_to_bf16(v0[3]);
        o[4] = (short)f32_to_bf16(v1[0]); o[5] = (short)f32_to_bf16(v1[1]);
        o[6] = (short)f32_to_bf16(v1[2]); o[7] = (short)f32_to_bf16(v1[3]);
        const int cdst = (c & ~7) | ((c & 7) ^ ((int)row & 7));
        *(bf16x8*)(out + (row * (long)cpr + cdst) * 8) = o;
    }
}

__device__ __forceinline__ void gload_lds16(const unsigned short* g, unsigned short* l) {
    __builtin_amdgcn_global_load_lds(
        (const __attribute__((address_space(1))) void*)g,
        (__attribute__((address_space(3))) void*)l, 16, 0, 0);
}

// Stage one 128x64 bf16 half-tile (16 KB): 2 global_load_lds x16 per thread.
// Source is PRE-SWIZZLED, so global read AND LDS dest are perfectly linear.
__device__ __forceinline__ void stage_half(const unsigned short* __restrict__ G,
                                           unsigned short* lds,
                                           int grow0, int gcol, int K, int tid) {
    const int wave = tid >> 6;
#pragma unroll
    for (int p = 0; p < 2; ++p) {
        const int s = tid + p * NTHREADS;            // 16B chunk 0..1023
        const int row = s >> 3;                      // 0..127
        const unsigned short* g = G + (size_t)(grow0 + row) * K + gcol + (s & 7) * 8;
        unsigned short* l = lds + (size_t)(wave * 64 + p * NTHREADS) * 8;
        gload_lds16(g, l);
    }
}

// R17: 32x32x16 MFMA with R13's LOOSE single-barrier tail-read schedule, plus
// MINIMAL code-motion pins at region edges:
//   phase = [STG | vmcnt? | sched_barrier | s_barrier | lgkm0(+"memory") |
//            sched_barrier | MFMA ∥ tail-reads (unfenced)]
// The pin BEFORE the barrier stops tail ds_reads sinking past it into the
// region where a restage's DMA write lands (R15's suspected race); the pin
// AFTER the lgkm0 stops the next tail reads hoisting above publication.
// Inside the region the MFMA/read interleave stays free (R13's win; R16's
// hard per-phase drains bunched all waves' LDS ops -> 2.5e7 cross-wave bank
// conflicts and 320us).
// Ring: A 1-phase-ahead (a0/a1); B 2-phases-ahead, period 4 (bs0..bs3).
// Stages: A1(t+1)@P1P2, B0(t+2)@P4P5, A0(t+2)@P6P7, B1(t+3)@P8x2. Publishes
// (vmcnt BEFORE the barrier of the same phase): P3 vmcnt(4) -> buf1-B,
// P4 vmcnt(2) -> buf1-A, P7 vmcnt(4) -> buf0-B(t+2), P8 vmcnt(4) -> buf0-A.
// All counted; never drained to 0 in the loop. Overwrite-vs-last-reader
// separation >= 1 full phase region + DMA latency (re-derived, see comments).
__global__ __launch_bounds__(NTHREADS, 2)
void gemm8p(const unsigned short* __restrict__ Abf, const unsigned short* __restrict__ Bbf,
            const float* __restrict__ bias, float* __restrict__ out,
            int M, int N, int K) {
    // [buf][half][128 rows][64 k] bf16 (swizzled layout) — 128 KB total
    __shared__ unsigned short sA[2][2][128 * 64];
    __shared__ unsigned short sB[2][2][128 * 64];

    const int tid  = threadIdx.x;
    const int lane = tid & 63;
    const int wave = tid >> 6;
    const int wm = wave >> 2;          // 0..1 : A-half / wave's 128-row band
    const int wn = wave & 3;           // 0..3 : 64-col band (B-half = wn>>1)
    const int li = lane & 31;          // row/col within a 32-block
    const int hi = lane >> 5;          // k-half of the 16-k step
    const int NT = K / BK;

    // Bijective XCD-chunk swizzle (T1); grid is (N/256, M/256).
    const int gx = gridDim.x;
    const int nwg = gx * gridDim.y;
    int lin = blockIdx.y * gx + blockIdx.x;
    if ((nwg & 7) == 0) lin = (lin & 7) * (nwg >> 3) + (lin >> 3);
    const int bm0 = (lin / gx) * BMN;
    const int bn0 = (lin % gx) * BMN;

    // Fragment-read offsets. kstep s covers k = s*16 + hi*8 + 0..7, i.e.
    // logical 16B-chunk 2s+hi; baked swizzle -> phys = (2s+hi) ^ (row&7),
    // row&7 = li&7 (block bases are multiples of 32). Per quarter-wave the
    // chunk value spans all 8 windows 2-lanes-each = conflict-free (m136),
    // same structure as R13's verified-0-conflict pattern.
    const int r7  = li & 7;
    const int kc0 = ((0 + hi) ^ r7) * 8;
    const int kc1 = ((2 + hi) ^ r7) * 8;
    const int kc2 = ((4 + hi) ^ r7) * 8;
    const int kc3 = ((6 + hi) ^ r7) * 8;
    const int Arow = li * 64;
    const int Brow = ((wn & 1) * 64 + li) * 64;

    const unsigned short* Ab0 = &sA[0][wm][0];
    const unsigned short* Ab1 = &sA[1][wm][0];
    const unsigned short* Bb0 = &sB[0][wn >> 1][0];
    const unsigned short* Bb1 = &sB[1][wn >> 1][0];

    // 8 accumulator tiles of 32x32: [b(4 row-blocks)][cb(2 col-blocks)]
    f32x16 acc[8];
    {
        f32x16 z;
#pragma unroll
        for (int e = 0; e < 16; ++e) z[e] = 0.0f;
#pragma unroll
        for (int i = 0; i < 8; ++i) acc[i] = z;
    }

    // Operand sets: A 1-phase-ahead ping-pong; B 2-phases-ahead, period 4.
    bf16x8 a0[4], a1[4], bs0[2], bs1[2], bs2[2], bs3[2];

#define RD_A32(dst, base, kc) { const unsigned short* _pa = (base); \
    _Pragma("unroll") for (int b = 0; b < 4; ++b) \
        dst[b] = *(const bf16x8*)&_pa[b * 2048 + Arow + (kc)]; }
#define RD_B32(dst, base, kc) { const unsigned short* _pb = (base); \
    _Pragma("unroll") for (int cb = 0; cb < 2; ++cb) \
        dst[cb] = *(const bf16x8*)&_pb[cb * 2048 + Brow + (kc)]; }

#define PH(aU, bU, RDS, STG, VMW) \
    STG \
    VMW \
    __builtin_amdgcn_sched_barrier(0); \
    __builtin_amdgcn_s_barrier(); \
    asm volatile("s_waitcnt lgkmcnt(0)" ::: "memory"); \
    __builtin_amdgcn_sched_barrier(0); \
    __builtin_amdgcn_s_setprio(1); \
    _Pragma("unroll") for (int b = 0; b < 4; ++b) \
    _Pragma("unroll") for (int cb = 0; cb < 2; ++cb) \
        acc[b * 2 + cb] = __builtin_amdgcn_mfma_f32_32x32x16_bf16(aU[b], bU[cb], acc[b * 2 + cb], 0, 0, 0); \
    __builtin_amdgcn_s_setprio(0); \
    RDS

    // ---- prologue: tile0 (4 halves) + tile1 B-halves; counted wait, no drain.
    stage_half(Abf, &sA[0][0][0], bm0,       0,  K, tid);
    stage_half(Abf, &sA[0][1][0], bm0 + 128, 0,  K, tid);
    stage_half(Bbf, &sB[0][0][0], bn0,       0,  K, tid);
    stage_half(Bbf, &sB[0][1][0], bn0 + 128, 0,  K, tid);
    stage_half(Bbf, &sB[1][0][0], bn0,       BK, K, tid);
    stage_half(Bbf, &sB[1][1][0], bn0 + 128, BK, K, tid);
    asm volatile("s_waitcnt vmcnt(4)" ::: "memory");  // tile0's 8 loads landed
    __builtin_amdgcn_s_barrier();
    __builtin_amdgcn_sched_barrier(0);
    // P1 operands + B 2-ahead pipeline warm-up (all tile0, published above)
    RD_A32(a0, Ab0, kc0)
    RD_B32(bs0, Bb0, kc0)
    RD_B32(bs1, Bb0, kc1)

    // ---- main loop: 2 K-tiles per iteration (buf0 = t, buf1 = t+1).
    // vmcnt bookkeeping (steady state, per wave, oldest-first):
    //   enter P1: [P8prev:4(sB1)]; P1 +2, P2 +2 -> 8
    //   P3 vmcnt(4): drains P8prev's 4 = buf1-B published. [P1:2,P2:2]
    //   P4 +2 then vmcnt(2): drains P1,P2 = buf1-A published. [P4:2]
    //   P5 +2, P6 +2, P7 +2 then vmcnt(4): drains P4,P5 = buf0-B(t+2). [P6:2,P7:2]
    //   P8 +4 then vmcnt(4): drains P6,P7 = buf0-A(t+2). [P8:4] = loop invariant.
    // Overwrite-vs-last-read-ISSUE separation (>=1 full phase + DMA latency):
    //   P1 stg sA1 vs Ab1 last read P7prev-tail; P4 stg sB0 vs Bb0 @P2-tail;
    //   P6 stg sA0 vs Ab0 @P3-tail; P8 stg sB1 vs Bb1 @P6-tail.
    for (int t = 0; t < NT; t += 2) {
        int u2 = t + 2; if (u2 >= NT) u2 -= NT;   // wrap stages = harmless dummies
        int u3 = t + 3; if (u3 >= NT) u3 -= NT;
        const int k1 = (t + 1) * BK, k2 = u2 * BK, k3 = u3 * BK;

        // P1: tile t s0; tail: A(s1,b0), B(s2,b0)
        PH(a0, bs0,
           RD_A32(a1, Ab0, kc1) RD_B32(bs2, Bb0, kc2),
           stage_half(Abf, &sA[1][0][0], bm0, k1, K, tid);, )

        // P2: s1; tail: A(s2,b0), B(s3,b0)
        PH(a1, bs1,
           RD_A32(a0, Ab0, kc2) RD_B32(bs3, Bb0, kc3),
           stage_half(Abf, &sA[1][1][0], bm0 + 128, k1, K, tid);, )

        // P3: s2; vmcnt(4) publishes buf1-B; tail: A(s3,b0), B(s0,b1)
        PH(a0, bs2,
           RD_A32(a1, Ab0, kc3) RD_B32(bs0, Bb1, kc0),
           , asm volatile("s_waitcnt vmcnt(4)" ::: "memory");)

        // P4: s3; vmcnt(2) publishes buf1-A; tail: A(s0,b1), B(s1,b1)
        PH(a1, bs3,
           RD_A32(a0, Ab1, kc0) RD_B32(bs1, Bb1, kc1),
           stage_half(Bbf, &sB[0][0][0], bn0, k2, K, tid);,
           asm volatile("s_waitcnt vmcnt(2)" ::: "memory");)

        // P5: tile t+1 s0; tail: A(s1,b1), B(s2,b1)
        PH(a0, bs0,
           RD_A32(a1, Ab1, kc1) RD_B32(bs2, Bb1, kc2),
           stage_half(Bbf, &sB[0][1][0], bn0 + 128, k2, K, tid);, )

        // P6: s1; tail: A(s2,b1), B(s3,b1)
        PH(a1, bs1,
           RD_A32(a0, Ab1, kc2) RD_B32(bs3, Bb1, kc3),
           stage_half(Abf, &sA[0][0][0], bm0, k2, K, tid);, )

        // P7: s2; vmcnt(4) publishes buf0-B(t+2); tail: A(s3,b1), B(s0,b0-next)
        PH(a0, bs2,
           RD_A32(a1, Ab1, kc3) RD_B32(bs0, Bb0, kc0),
           stage_half(Abf, &sA[0][1][0], bm0 + 128, k2, K, tid);,
           asm volatile("s_waitcnt vmcnt(4)" ::: "memory");)

        // P8: s3; vmcnt(4) publishes buf0-A(t+2); tail: A(s0,b0-next), B(s1,b0-next)
        PH(a1, bs3,
           RD_A32(a0, Ab0, kc0) RD_B32(bs1, Bb0, kc1),
           stage_half(Bbf, &sB[1][0][0], bn0, k3, K, tid);
           stage_half(Bbf, &sB[1][1][0], bn0 + 128, k3, K, tid);,
           asm volatile("s_waitcnt vmcnt(4)" ::: "memory");)
    }

    asm volatile("s_waitcnt vmcnt(0) lgkmcnt(0)" ::: "memory");  // drain

    // ---- epilogue: + bias, final mantissa round, store fp32.
    // 32x32 C/D layout (verified m74/m101): col = lane&31,
    // row = (e&3) + 8*(e>>2) + 4*(lane>>5).
#pragma unroll
    for (int b = 0; b < 4; ++b) {
        const int row0 = bm0 + wm * 128 + b * 32 + 4 * hi;
#pragma unroll
        for (int cb = 0; cb < 2; ++cb) {
            const int col = bn0 + wn * 64 + cb * 32 + li;
            const float bv = bias[col];
#pragma unroll
            for (int g = 0; g < 4; ++g)
#pragma unroll
                for (int r = 0; r < 4; ++r)
                    out[(size_t)(row0 + g * 8 + r) * N + col] =
                        round_m10(acc[b * 2 + cb][g * 4 + r] + bv);
        }
    }
#undef RD_A32
#undef RD_B32
#undef PH
}

// Fallback: fused fp32->bf16 128^2 kernel (only for shapes the main path rejects).
__global__ __launch_bounds__(256)
void gemm_fallback(const float* __restrict__ A, const float* __restrict__ B,
                   const float* __restrict__ bias, float* __restrict__ out,
                   int M, int N, int K) {
    __shared__ unsigned short lds_a[128 * 64];
    __shared__ unsigned short lds_b[128 * 64];
    const int tid = threadIdx.x, lane = tid & 63, wave = tid >> 6;
    const int wm = wave >> 1, wn = wave & 1;
    const int bm0 = blockIdx.y * 128, bn0 = blockIdx.x * 128;
    const int lrow = lane & 15, lkg = lane >> 4;
    f32x4 acc[4][4];
    const f32x4 zero = {0.f, 0.f, 0.f, 0.f};
#pragma unroll
    for (int i = 0; i < 4; ++i)
#pragma unroll
        for (int j = 0; j < 4; ++j) acc[i][j] = zero;
    for (int kb = 0; kb < K / 64; ++kb) {
        const int kt = kb * 64;
        const int r0 = tid >> 4, c0 = (tid & 15) << 2;
#pragma unroll
        for (int p = 0; p < 8; ++p) {
            const int r = p * 16 + r0;
            f32x4 va = *(const f32x4*)(A + (size_t)(bm0 + r) * K + kt + c0);
            f32x4 vb = *(const f32x4*)(B + (size_t)(bn0 + r) * K + kt + c0);
            ushort4 ua, ub;
            ua.x = f32_to_bf16(va[0]); ua.y = f32_to_bf16(va[1]);
            ua.z = f32_to_bf16(va[2]); ua.w = f32_to_bf16(va[3]);
            ub.x = f32_to_bf16(vb[0]); ub.y = f32_to_bf16(vb[1]);
            ub.z = f32_to_bf16(vb[2]); ub.w = f32_to_bf16(vb[3]);
            *(ushort4*)(&lds_a[r * 64 + c0]) = ua;
            *(ushort4*)(&lds_b[r * 64 + c0]) = ub;
        }
        __syncthreads();
#pragma unroll
        for (int kk = 0; kk < 64; kk += 32) {
            bf16x8 af[4], bfr[4];
#pragma unroll
            for (int i = 0; i < 4; ++i)
                af[i] = *(const bf16x8*)(&lds_a[(wm * 64 + i * 16 + lrow) * 64 + kk + lkg * 8]);
#pragma unroll
            for (int j = 0; j < 4; ++j)
                bfr[j] = *(const bf16x8*)(&lds_b[(wn * 64 + j * 16 + lrow) * 64 + kk + lkg * 8]);
#pragma unroll
            for (int i = 0; i < 4; ++i)
#pragma unroll
                for (int j = 0; j < 4; ++j)
                    acc[i][j] = __builtin_amdgcn_mfma_f32_16x16x32_bf16(af[i], bfr[j], acc[i][j], 0, 0, 0);
        }
        __syncthreads();
    }
#pragma unroll
    for (int i = 0; i < 4; ++i) {
        const int row0 = bm0 + wm * 64 + i * 16 + lkg * 4;
#pragma unroll
        for (int j = 0; j < 4; ++j) {
            const int col = bn0 + wn * 64 + j * 16 + lrow;
            const float bv = bias[col];
#pragma unroll
            for (int r = 0; r < 4; ++r)
                out[(size_t)(row0 + r) * N + col] = round_m10(acc[i][j][r] + bv);
        }
    }
}

extern "C" void kernel_launch(void* const* d_in, const int* in_sizes, int n_in,
                              void* d_out, int out_size, void* d_ws, size_t ws_size,
                              hipStream_t stream) {
    const float* x    = (const float*)d_in[0];   // [M, K]
    const float* w    = (const float*)d_in[1];   // [N, K]
    const float* bias = (const float*)d_in[2];   // [N]
    float* out = (float*)d_out;                  // [M, N]

    const int N = in_sizes[2];
    const int K = in_sizes[1] / N;
    const int M = in_sizes[0] / K;

    const size_t nx = (size_t)M * K;
    const size_t nw = (size_t)N * K;
    const size_t need = (nx + nw) * sizeof(unsigned short);
    const int NT = K / BK;

    if (ws_size >= need && (M % BMN) == 0 && (N % BMN) == 0 && (K % BK) == 0 &&
        NT >= 4 && (NT % 2) == 0) {
        unsigned short* xb = (unsigned short*)d_ws;
        unsigned short* wb = xb + nx;
        const int cpr = K / 8;
        convert_f32_bf16_swz<<<2048, 256, 0, stream>>>(x, xb, (long)(nx / 8), cpr);
        convert_f32_bf16_swz<<<2048, 256, 0, stream>>>(w, wb, (long)(nw / 8), cpr);
        dim3 grid(N / BMN, M / BMN);
        gemm8p<<<grid, NTHREADS, 0, stream>>>(xb, wb, bias, out, M, N, K);
    } else {
        dim3 grid(N / 128, M / 128);
        gemm_fallback<<<grid, 256, 0, stream>>>(x, w, bias, out, M, N, K);
    }
}

// Round 5
// 310.145 us; speedup vs baseline: 1.0772x; 1.0640x over previous
//
#include <hip/hip_runtime.h>
#include <stdint.h>
#include <stddef.h>

typedef __attribute__((ext_vector_type(4))) float f32x4;
typedef __attribute__((ext_vector_type(16))) float f32x16;
typedef __attribute__((ext_vector_type(8))) short bf16x8;

#define BMN 256      // block tile M = N
#define BK  64       // K per K-tile
#define NTHREADS 512

// Round-to-nearest-even fp32 mantissa to 10 bits (shift = 23-10 = 13).
__device__ __forceinline__ float round_m10(float x) {
    int b = __float_as_int(x);
    int rb = ((b >> 13) & 1) + 0x0FFF;
    b = (b + rb) & (int)0xFFFFE000;
    return __int_as_float(b);
}

__device__ __forceinline__ unsigned short f32_to_bf16(float x) {
    unsigned int u = __float_as_uint(x);
    u += 0x7FFFu + ((u >> 16) & 1u);
    return (unsigned short)(u >> 16);
}

// R18 convert: fp32 -> bf16 PANEL-TRANSPOSED workspace. ws is stored as 16B
// chunks indexed [panel P = row/128][k-chunk c = k/8][r = row%128]:
//   ws_chunk = (P*cpr + c)*128 + r
// so a 128-row x 64-k half-tile is ONE contiguous 16KB span -> gemm staging
// reads ws linearly (perfect coalescing) and the LDS image lands in
// "fragment order": every MFMA fragment read is base + lane*16 (1024B
// contiguous per wave) = conflict-free by construction at any granularity.
// The transpose is done via a padded LDS tile, coalesced on both sides.
__global__ void convert_f32_bf16_tr(const float* __restrict__ in,
                                    unsigned short* __restrict__ out,
                                    int rows, int K) {
    __shared__ unsigned short t[128 * 72];   // [r][64 + 8 pad] ushorts
    const int cpr = K >> 3;                  // 16B chunks per row
    const int nct = cpr >> 3;                // 64-col tiles per panel-row
    const int ntiles = (rows >> 7) * nct;
    const int tid = threadIdx.x;             // 256 threads
    for (int tile = blockIdx.x; tile < ntiles; tile += gridDim.x) {
        const int P = tile / nct, cb = tile - P * nct;
        const int c0 = cb * 8;               // first k-chunk of this tile
        // phase 1: coalesced f32x4 reads, convert, store to padded LDS
#pragma unroll
        for (int i = 0; i < 8; ++i) {
            const int idx = tid + i * 256;   // 0..2047
            const int r = idx >> 4, q = idx & 15;
            f32x4 v = *(const f32x4*)(in + (size_t)(P * 128 + r) * K + c0 * 8 + q * 4);
            ushort4 u;
            u.x = f32_to_bf16(v[0]); u.y = f32_to_bf16(v[1]);
            u.z = f32_to_bf16(v[2]); u.w = f32_to_bf16(v[3]);
            *(ushort4*)&t[r * 72 + q * 4] = u;
        }
        __syncthreads();
        // phase 2: write out in (c, r) order -> contiguous 16B chunks
#pragma unroll
        for (int i = 0; i < 4; ++i) {
            const int o = tid + i * 256;     // 0..1023
            const int c = o >> 7, r = o & 127;
            bf16x8 w = *(const bf16x8*)&t[r * 72 + c * 8];
            *(bf16x8*)(out + ((size_t)(P * cpr + c0 + c) * 128 + r) * 8) = w;
        }
        __syncthreads();
    }
}

__device__ __forceinline__ void gload_lds16(const unsigned short* g, unsigned short* l) {
    __builtin_amdgcn_global_load_lds(
        (const __attribute__((address_space(1))) void*)g,
        (__attribute__((address_space(3))) void*)l, 16, 0, 0);
}

// Stage one half-tile (16 KB = 1024 chunks): ws span is contiguous, LDS dest
// linear; thread t moves chunks t and t+512. 2 global_load_lds x16 per thread.
__device__ __forceinline__ void stage_half(const unsigned short* __restrict__ G,
                                           unsigned short* lds,
                                           size_t base_chunk, int tid) {
    const int wave = tid >> 6;
#pragma unroll
    for (int p = 0; p < 2; ++p) {
        const unsigned short* g = G + (base_chunk + (size_t)(tid + p * NTHREADS)) * 8;
        unsigned short* l = lds + (size_t)(wave * 64 + p * NTHREADS) * 8;
        gload_lds16(g, l);
    }
}

// R18: 32x32x16 MFMA + fragment-order LDS (conflict-free reads by
// construction) + R17's pinned loose single-barrier schedule:
//   phase = [STG | vmcnt? | sched_barrier | s_barrier | lgkm0(+"memory") |
//            sched_barrier | MFMA ∥ tail-reads (unfenced)]
// LDS half-tile layout: [c2 = 2s+hi (k-chunk)][row r 0..127] 16B chunks.
// Fragment read for kstep s: lane l reads slot c2(s,hi)*128 + b*32 + li ->
// per 32-lane half a contiguous 512B run; all 32 banks hit exactly once per
// 8 lanes (identical shape to the DMA-write pattern, measured 0 conflicts).
// Ring: A 1-phase-ahead (a0/a1); B 2-phases-ahead, period 4 (bs0..bs3).
// Stages: A1(t+1)@P1P2, B0(t+2)@P4P5, A0(t+2)@P6P7, B1(t+3)@P8x2. Publishes:
// P3 vmcnt(4) -> buf1-B, P4 vmcnt(2) -> buf1-A, P7 vmcnt(4) -> buf0-B(t+2),
// P8 vmcnt(4) -> buf0-A. Counted; never drained to 0 in the loop.
__global__ __launch_bounds__(NTHREADS, 2)
void gemm8p(const unsigned short* __restrict__ Abf, const unsigned short* __restrict__ Bbf,
            const float* __restrict__ bias, float* __restrict__ out,
            int M, int N, int K) {
    // [buf][half][1024 chunks of 16B] bf16 — 128 KB total
    __shared__ unsigned short sA[2][2][128 * 64];
    __shared__ unsigned short sB[2][2][128 * 64];

    const int tid  = threadIdx.x;
    const int lane = tid & 63;
    const int wave = tid >> 6;
    const int wm = wave >> 2;          // 0..1 : A-half / wave's 128-row band
    const int wn = wave & 3;           // 0..3 : 64-col band (B-half = wn>>1)
    const int li = lane & 31;          // row/col within a 32-block
    const int hi = lane >> 5;          // k-half of the 16-k step
    const int NT = K / BK;
    const int cpr = K >> 3;

    // Bijective XCD-chunk swizzle (T1); grid is (N/256, M/256).
    const int gx = gridDim.x;
    const int nwg = gx * gridDim.y;
    int lin = blockIdx.y * gx + blockIdx.x;
    if ((nwg & 7) == 0) lin = (lin & 7) * (nwg >> 3) + (lin >> 3);
    const int bm0 = (lin / gx) * BMN;
    const int bn0 = (lin % gx) * BMN;
    const int pm0 = bm0 >> 7;          // first A panel of this block
    const int pn0 = bn0 >> 7;          // first B panel of this block

    // Fragment-order read offsets (ushorts): slot = (2s+hi)*128 + row, x8.
    const int lo8 = li * 8;
    const int kf0 = hi * 1024 + lo8;           // s = 0
    const int kf1 = kf0 + 2048;                // s = 1
    const int kf2 = kf0 + 4096;                // s = 2
    const int kf3 = kf0 + 6144;                // s = 3
    const int bsel = (wn & 1) * 512;           // B col-half select (64 rows)

    const unsigned short* Ab0 = &sA[0][wm][0];
    const unsigned short* Ab1 = &sA[1][wm][0];
    const unsigned short* Bb0 = &sB[0][wn >> 1][0];
    const unsigned short* Bb1 = &sB[1][wn >> 1][0];

    // 8 accumulator tiles of 32x32: [b(4 row-blocks)][cb(2 col-blocks)]
    f32x16 acc[8];
    {
        f32x16 z;
#pragma unroll
        for (int e = 0; e < 16; ++e) z[e] = 0.0f;
#pragma unroll
        for (int i = 0; i < 8; ++i) acc[i] = z;
    }

    // Operand sets: A 1-phase-ahead ping-pong; B 2-phases-ahead, period 4.
    bf16x8 a0[4], a1[4], bs0[2], bs1[2], bs2[2], bs3[2];

#define RD_A32(dst, base, kf) { const unsigned short* _pa = (base); \
    _Pragma("unroll") for (int b = 0; b < 4; ++b) \
        dst[b] = *(const bf16x8*)&_pa[(kf) + b * 256]; }
#define RD_B32(dst, base, kf) { const unsigned short* _pb = (base); \
    _Pragma("unroll") for (int cb = 0; cb < 2; ++cb) \
        dst[cb] = *(const bf16x8*)&_pb[(kf) + bsel + cb * 256]; }

// Half-tile base chunk in ws: panel p, k-tile column (kk>>3).
#define A_CH(h, kk) (((size_t)(pm0 + (h)) * cpr + ((kk) >> 3)) * 128)
#define B_CH(h, kk) (((size_t)(pn0 + (h)) * cpr + ((kk) >> 3)) * 128)

#define PH(aU, bU, RDS, STG, VMW) \
    STG \
    VMW \
    __builtin_amdgcn_sched_barrier(0); \
    __builtin_amdgcn_s_barrier(); \
    asm volatile("s_waitcnt lgkmcnt(0)" ::: "memory"); \
    __builtin_amdgcn_sched_barrier(0); \
    __builtin_amdgcn_s_setprio(1); \
    _Pragma("unroll") for (int b = 0; b < 4; ++b) \
    _Pragma("unroll") for (int cb = 0; cb < 2; ++cb) \
        acc[b * 2 + cb] = __builtin_amdgcn_mfma_f32_32x32x16_bf16(aU[b], bU[cb], acc[b * 2 + cb], 0, 0, 0); \
    __builtin_amdgcn_s_setprio(0); \
    RDS

    // ---- prologue: tile0 (4 halves) + tile1 B-halves; counted wait, no drain.
    stage_half(Abf, &sA[0][0][0], A_CH(0, 0), tid);
    stage_half(Abf, &sA[0][1][0], A_CH(1, 0), tid);
    stage_half(Bbf, &sB[0][0][0], B_CH(0, 0), tid);
    stage_half(Bbf, &sB[0][1][0], B_CH(1, 0), tid);
    stage_half(Bbf, &sB[1][0][0], B_CH(0, BK), tid);
    stage_half(Bbf, &sB[1][1][0], B_CH(1, BK), tid);
    asm volatile("s_waitcnt vmcnt(4)" ::: "memory");  // tile0's 8 loads landed
    __builtin_amdgcn_s_barrier();
    __builtin_amdgcn_sched_barrier(0);
    // P1 operands + B 2-ahead pipeline warm-up (all tile0, published above)
    RD_A32(a0, Ab0, kf0)
    RD_B32(bs0, Bb0, kf0)
    RD_B32(bs1, Bb0, kf1)

    // ---- main loop: 2 K-tiles per iteration (buf0 = t, buf1 = t+1).
    // vmcnt bookkeeping (steady state, per wave, oldest-first):
    //   enter P1: [P8prev:4(sB1)]; P1 +2, P2 +2 -> 8
    //   P3 vmcnt(4): drains P8prev's 4 = buf1-B published. [P1:2,P2:2]
    //   P4 +2 then vmcnt(2): drains P1,P2 = buf1-A published. [P4:2]
    //   P5 +2, P6 +2, P7 +2 then vmcnt(4): drains P4,P5 = buf0-B(t+2). [P6:2,P7:2]
    //   P8 +4 then vmcnt(4): drains P6,P7 = buf0-A(t+2). [P8:4] = loop invariant.
    // Overwrite-vs-last-read-ISSUE separation (>=1 full phase + DMA latency):
    //   P1 stg sA1 vs Ab1 last read P7prev-tail; P4 stg sB0 vs Bb0 @P2-tail;
    //   P6 stg sA0 vs Ab0 @P3-tail; P8 stg sB1 vs Bb1 @P6-tail.
    for (int t = 0; t < NT; t += 2) {
        int u2 = t + 2; if (u2 >= NT) u2 -= NT;   // wrap stages = harmless dummies
        int u3 = t + 3; if (u3 >= NT) u3 -= NT;
        const int k1 = (t + 1) * BK, k2 = u2 * BK, k3 = u3 * BK;

        // P1: tile t s0; tail: A(s1,b0), B(s2,b0)
        PH(a0, bs0,
           RD_A32(a1, Ab0, kf1) RD_B32(bs2, Bb0, kf2),
           stage_half(Abf, &sA[1][0][0], A_CH(0, k1), tid);, )

        // P2: s1; tail: A(s2,b0), B(s3,b0)
        PH(a1, bs1,
           RD_A32(a0, Ab0, kf2) RD_B32(bs3, Bb0, kf3),
           stage_half(Abf, &sA[1][1][0], A_CH(1, k1), tid);, )

        // P3: s2; vmcnt(4) publishes buf1-B; tail: A(s3,b0), B(s0,b1)
        PH(a0, bs2,
           RD_A32(a1, Ab0, kf3) RD_B32(bs0, Bb1, kf0),
           , asm volatile("s_waitcnt vmcnt(4)" ::: "memory");)

        // P4: s3; vmcnt(2) publishes buf1-A; tail: A(s0,b1), B(s1,b1)
        PH(a1, bs3,
           RD_A32(a0, Ab1, kf0) RD_B32(bs1, Bb1, kf1),
           stage_half(Bbf, &sB[0][0][0], B_CH(0, k2), tid);,
           asm volatile("s_waitcnt vmcnt(2)" ::: "memory");)

        // P5: tile t+1 s0; tail: A(s1,b1), B(s2,b1)
        PH(a0, bs0,
           RD_A32(a1, Ab1, kf1) RD_B32(bs2, Bb1, kf2),
           stage_half(Bbf, &sB[0][1][0], B_CH(1, k2), tid);, )

        // P6: s1; tail: A(s2,b1), B(s3,b1)
        PH(a1, bs1,
           RD_A32(a0, Ab1, kf2) RD_B32(bs3, Bb1, kf3),
           stage_half(Abf, &sA[0][0][0], A_CH(0, k2), tid);, )

        // P7: s2; vmcnt(4) publishes buf0-B(t+2); tail: A(s3,b1), B(s0,b0-next)
        PH(a0, bs2,
           RD_A32(a1, Ab1, kf3) RD_B32(bs0, Bb0, kf0),
           stage_half(Abf, &sA[0][1][0], A_CH(1, k2), tid);,
           asm volatile("s_waitcnt vmcnt(4)" ::: "memory");)

        // P8: s3; vmcnt(4) publishes buf0-A(t+2); tail: A(s0,b0-next), B(s1,b0-next)
        PH(a1, bs3,
           RD_A32(a0, Ab0, kf0) RD_B32(bs1, Bb0, kf1),
           stage_half(Bbf, &sB[1][0][0], B_CH(0, k3), tid);
           stage_half(Bbf, &sB[1][1][0], B_CH(1, k3), tid);,
           asm volatile("s_waitcnt vmcnt(4)" ::: "memory");)
    }

    asm volatile("s_waitcnt vmcnt(0) lgkmcnt(0)" ::: "memory");  // drain

    // ---- epilogue: + bias, final mantissa round, store fp32.
    // 32x32 C/D layout (verified m74/m101): col = lane&31,
    // row = (e&3) + 8*(e>>2) + 4*(lane>>5).
#pragma unroll
    for (int b = 0; b < 4; ++b) {
        const int row0 = bm0 + wm * 128 + b * 32 + 4 * hi;
#pragma unroll
        for (int cb = 0; cb < 2; ++cb) {
            const int col = bn0 + wn * 64 + cb * 32 + li;
            const float bv = bias[col];
#pragma unroll
            for (int g = 0; g < 4; ++g)
#pragma unroll
                for (int r = 0; r < 4; ++r)
                    out[(size_t)(row0 + g * 8 + r) * N + col] =
                        round_m10(acc[b * 2 + cb][g * 4 + r] + bv);
        }
    }
#undef RD_A32
#undef RD_B32
#undef A_CH
#undef B_CH
#undef PH
}

// Fallback: fused fp32->bf16 128^2 kernel (only for shapes the main path rejects).
__global__ __launch_bounds__(256)
void gemm_fallback(const float* __restrict__ A, const float* __restrict__ B,
                   const float* __restrict__ bias, float* __restrict__ out,
                   int M, int N, int K) {
    __shared__ unsigned short lds_a[128 * 64];
    __shared__ unsigned short lds_b[128 * 64];
    const int tid = threadIdx.x, lane = tid & 63, wave = tid >> 6;
    const int wm = wave >> 1, wn = wave & 1;
    const int bm0 = blockIdx.y * 128, bn0 = blockIdx.x * 128;
    const int lrow = lane & 15, lkg = lane >> 4;
    f32x4 acc[4][4];
    const f32x4 zero = {0.f, 0.f, 0.f, 0.f};
#pragma unroll
    for (int i = 0; i < 4; ++i)
#pragma unroll
        for (int j = 0; j < 4; ++j) acc[i][j] = zero;
    for (int kb = 0; kb < K / 64; ++kb) {
        const int kt = kb * 64;
        const int r0 = tid >> 4, c0 = (tid & 15) << 2;
#pragma unroll
        for (int p = 0; p < 8; ++p) {
            const int r = p * 16 + r0;
            f32x4 va = *(const f32x4*)(A + (size_t)(bm0 + r) * K + kt + c0);
            f32x4 vb = *(const f32x4*)(B + (size_t)(bn0 + r) * K + kt + c0);
            ushort4 ua, ub;
            ua.x = f32_to_bf16(va[0]); ua.y = f32_to_bf16(va[1]);
            ua.z = f32_to_bf16(va[2]); ua.w = f32_to_bf16(va[3]);
            ub.x = f32_to_bf16(vb[0]); ub.y = f32_to_bf16(vb[1]);
            ub.z = f32_to_bf16(vb[2]); ub.w = f32_to_bf16(vb[3]);
            *(ushort4*)(&lds_a[r * 64 + c0]) = ua;
            *(ushort4*)(&lds_b[r * 64 + c0]) = ub;
        }
        __syncthreads();
#pragma unroll
        for (int kk = 0; kk < 64; kk += 32) {
            bf16x8 af[4], bfr[4];
#pragma unroll
            for (int i = 0; i < 4; ++i)
                af[i] = *(const bf16x8*)(&lds_a[(wm * 64 + i * 16 + lrow) * 64 + kk + lkg * 8]);
#pragma unroll
            for (int j = 0; j < 4; ++j)
                bfr[j] = *(const bf16x8*)(&lds_b[(wn * 64 + j * 16 + lrow) * 64 + kk + lkg * 8]);
#pragma unroll
            for (int i = 0; i < 4; ++i)
#pragma unroll
                for (int j = 0; j < 4; ++j)
                    acc[i][j] = __builtin_amdgcn_mfma_f32_16x16x32_bf16(af[i], bfr[j], acc[i][j], 0, 0, 0);
        }
        __syncthreads();
    }
#pragma unroll
    for (int i = 0; i < 4; ++i) {
        const int row0 = bm0 + wm * 64 + i * 16 + lkg * 4;
#pragma unroll
        for (int j = 0; j < 4; ++j) {
            const int col = bn0 + wn * 64 + j * 16 + lrow;
            const float bv = bias[col];
#pragma unroll
            for (int r = 0; r < 4; ++r)
                out[(size_t)(row0 + r) * N + col] = round_m10(acc[i][j][r] + bv);
        }
    }
}

extern "C" void kernel_launch(void* const* d_in, const int* in_sizes, int n_in,
                              void* d_out, int out_size, void* d_ws, size_t ws_size,
                              hipStream_t stream) {
    const float* x    = (const float*)d_in[0];   // [M, K]
    const float* w    = (const float*)d_in[1];   // [N, K]
    const float* bias = (const float*)d_in[2];   // [N]
    float* out = (float*)d_out;                  // [M, N]

    const int N = in_sizes[2];
    const int K = in_sizes[1] / N;
    const int M = in_sizes[0] / K;

    const size_t nx = (size_t)M * K;
    const size_t nw = (size_t)N * K;
    const size_t need = (nx + nw) * sizeof(unsigned short);
    const int NT = K / BK;

    if (ws_size >= need && (M % BMN) == 0 && (N % BMN) == 0 && (K % BK) == 0 &&
        NT >= 4 && (NT % 2) == 0) {
        unsigned short* xb = (unsigned short*)d_ws;
        unsigned short* wb = xb + nx;
        convert_f32_bf16_tr<<<2048, 256, 0, stream>>>(x, xb, M, K);
        convert_f32_bf16_tr<<<2048, 256, 0, stream>>>(w, wb, N, K);
        dim3 grid(N / BMN, M / BMN);
        gemm8p<<<grid, NTHREADS, 0, stream>>>(xb, wb, bias, out, M, N, K);
    } else {
        dim3 grid(N / 128, M / 128);
        gemm_fallback<<<grid, 256, 0, stream>>>(x, w, bias, out, M, N, K);
    }
}

// Round 6
// 271.346 us; speedup vs baseline: 1.2312x; 1.1430x over previous
//
#include <hip/hip_runtime.h>
#include <stdint.h>
#include <stddef.h>

typedef __attribute__((ext_vector_type(4))) float f32x4;
typedef __attribute__((ext_vector_type(8))) short bf16x8;

#define BMN 256      // block tile M = N
#define BK  64       // K per K-tile
#define NTHREADS 512

// Round-to-nearest-even fp32 mantissa to 10 bits (shift = 23-10 = 13).
__device__ __forceinline__ float round_m10(float x) {
    int b = __float_as_int(x);
    int rb = ((b >> 13) & 1) + 0x0FFF;
    b = (b + rb) & (int)0xFFFFE000;
    return __int_as_float(b);
}

__device__ __forceinline__ unsigned short f32_to_bf16(float x) {
    unsigned int u = __float_as_uint(x);
    u += 0x7FFFu + ((u >> 16) & 1u);
    return (unsigned short)(u >> 16);
}

// fp32 -> bf16 with the 3-bit bank swizzle BAKED IN: the 16B chunk at logical
// (row, c) is stored at (row, (c & ~7) | ((c&7) ^ (row&7))). Permutation acts
// within each 128B row-window; all tile offsets are 128B-aligned, so LDS
// staging reads LINEARLY and inherits the swizzle (rule #21).
// R19: FUSED single launch for both tensors (x then w) — removes one
// full-grid launch boundary; per-chunk body identical to the verified R13
// convert. Branch is wave-uniform except at the x/w seam (1 wave).
__global__ void convert2_f32_bf16_swz(const float* __restrict__ inx,
                                      unsigned short* __restrict__ outx,
                                      const float* __restrict__ inw,
                                      unsigned short* __restrict__ outw,
                                      long nx8, long ntot, int cpr) {
    long g = (long)blockIdx.x * blockDim.x + threadIdx.x;
    const long stride = (long)gridDim.x * blockDim.x;
    for (; g < ntot; g += stride) {
        const float* in;
        unsigned short* out;
        long gg;
        if (g < nx8) { in = inx; out = outx; gg = g; }
        else         { in = inw; out = outw; gg = g - nx8; }
        const long row = gg / cpr;
        const int c = (int)(gg - row * cpr);
        const float* p = in + gg * 8;
        f32x4 v0 = *(const f32x4*)p;
        f32x4 v1 = *(const f32x4*)(p + 4);
        bf16x8 o;
        o[0] = (short)f32_to_bf16(v0[0]); o[1] = (short)f32_to_bf16(v0[1]);
        o[2] = (short)f32_to_bf16(v0[2]); o[3] = (short)f32_to_bf16(v0[3]);
        o[4] = (short)f32_to_bf16(v1[0]); o[5] = (short)f32_to_bf16(v1[1]);
        o[6] = (short)f32_to_bf16(v1[2]); o[7] = (short)f32_to_bf16(v1[3]);
        const int cdst = (c & ~7) | ((c & 7) ^ ((int)row & 7));
        *(bf16x8*)(out + (row * (long)cpr + cdst) * 8) = o;
    }
}

__device__ __forceinline__ void gload_lds16(const unsigned short* g, unsigned short* l) {
    __builtin_amdgcn_global_load_lds(
        (const __attribute__((address_space(1))) void*)g,
        (__attribute__((address_space(3))) void*)l, 16, 0, 0);
}

// Stage one 128x64 bf16 half-tile (16 KB): 2 global_load_lds x16 per thread.
// Source is PRE-SWIZZLED, so global read AND LDS dest are perfectly linear.
__device__ __forceinline__ void stage_half(const unsigned short* __restrict__ G,
                                           unsigned short* lds,
                                           int grow0, int gcol, int K, int tid) {
    const int wave = tid >> 6;
#pragma unroll
    for (int p = 0; p < 2; ++p) {
        const int s = tid + p * NTHREADS;            // 16B chunk 0..1023
        const int row = s >> 3;                      // 0..127
        const unsigned short* g = G + (size_t)(grow0 + row) * K + gcol + (s & 7) * 8;
        unsigned short* l = lds + (size_t)(wave * 64 + p * NTHREADS) * 8;
        gload_lds16(g, l);
    }
}

// R13 single-barrier 8-phase + READ-AHEAD: phase p's operands were read in
// phase p-1's POST-barrier region (during MFMA), so the LDS queue drains
// under the matrix pipe. Phase = [stage|vmcnt?] barrier [lgkm0|MFMA|read p+1].
// (Verbatim harness-verified R13: 244 µs, MfmaUtil 50.3, 0 bank conflicts.
// Experiment ledger: R14 head-read pins -35µs worse; R15 32x32 loose RACED;
// R16 32x32 airtight 320µs; R17 32x32 pinned 313µs (2.5e7 conflicts from the
// 32x32 read pattern itself); R18 32x32 conflict-free-by-construction 276µs
// -> 16x16 R13 wins; 32x32 line closed.)
__global__ __launch_bounds__(NTHREADS, 2)
void gemm8p(const unsigned short* __restrict__ Abf, const unsigned short* __restrict__ Bbf,
            const float* __restrict__ bias, float* __restrict__ out,
            int M, int N, int K) {
    // [buf][half][128 rows][64 k] bf16 (swizzled layout) — 128 KB total
    __shared__ unsigned short sA[2][2][128 * 64];
    __shared__ unsigned short sB[2][2][128 * 64];

    const int tid  = threadIdx.x;
    const int lane = tid & 63;
    const int wave = tid >> 6;
    const int wm = wave >> 2;          // 0..1 : A-half / wave's 128-row band
    const int wn = wave & 3;           // 0..3 : 64-col band (B-half = wn>>1)
    const int lrow = lane & 15;
    const int lkg  = lane >> 4;
    const int NT = K / BK;

    // Bijective XCD-chunk swizzle (T1); grid is (N/256, M/256).
    const int gx = gridDim.x;
    const int nwg = gx * gridDim.y;
    int lin = blockIdx.y * gx + blockIdx.x;
    if ((nwg & 7) == 0) lin = (lin & 7) * (nwg >> 3) + (lin >> 3);
    const int bm0 = (lin / gx) * BMN;
    const int bn0 = (lin % gx) * BMN;

    // Conflict-free fragment-read offsets: phys chunk = logical ^ (lrow&7).
    const int r7   = lrow & 7;
    const int lco0 = (lkg ^ r7) * 8;        // kk = 0
    const int lco1 = lco0 ^ 32;             // kk = 32 (XOR: carry-free)
    const int Aoff0 = lrow * 64 + lco0;
    const int Aoff1 = lrow * 64 + lco1;
    const int Boff0 = ((wn & 1) * 64 + lrow) * 64 + lco0;
    const int Boff1 = ((wn & 1) * 64 + lrow) * 64 + lco1;

    const unsigned short* Ab0 = &sA[0][wm][0];
    const unsigned short* Ab1 = &sA[1][wm][0];
    const unsigned short* Bb0 = &sB[0][wn >> 1][0];
    const unsigned short* Bb1 = &sB[1][wn >> 1][0];

    f32x4 acc[8][4];
    const f32x4 zero = {0.f, 0.f, 0.f, 0.f};
#pragma unroll
    for (int i = 0; i < 8; ++i)
#pragma unroll
        for (int j = 0; j < 4; ++j) acc[i][j] = zero;

    // Ping-pong operand sets: A alternates per phase; B per 2 phases.
    bf16x8 aS0[4], aS1[4], bS0[4], bS1[4];

#define RD_A(dst, base, q, off) { const unsigned short* _pa = (base); \
    _Pragma("unroll") for (int i = 0; i < 4; ++i) \
        dst[i] = *(const bf16x8*)&_pa[((q) * 4 + i) * 1024 + (off)]; }
#define RD_B(dst, base, off) { const unsigned short* _pb = (base); \
    _Pragma("unroll") for (int j = 0; j < 4; ++j) \
        dst[j] = *(const bf16x8*)&_pb[j * 1024 + (off)]; }

// Single barrier per phase; reads for NEXT phase issued after this MFMA.
#define PH(q, aU, bU, RDS, STG, VMW) \
    STG \
    VMW \
    __builtin_amdgcn_s_barrier(); \
    asm volatile("s_waitcnt lgkmcnt(0)"); \
    __builtin_amdgcn_sched_barrier(0); \
    __builtin_amdgcn_s_setprio(1); \
    _Pragma("unroll") for (int i = 0; i < 4; ++i) \
    _Pragma("unroll") for (int j = 0; j < 4; ++j) \
        acc[(q) * 4 + i][j] = __builtin_amdgcn_mfma_f32_16x16x32_bf16(aU[i], bU[j], acc[(q) * 4 + i][j], 0, 0, 0); \
    __builtin_amdgcn_s_setprio(0); \
    RDS

    // ---- prologue: tile0 (4 halves) + tile1 B-halves; counted wait, no drain.
    stage_half(Abf, &sA[0][0][0], bm0,       0,  K, tid);
    stage_half(Abf, &sA[0][1][0], bm0 + 128, 0,  K, tid);
    stage_half(Bbf, &sB[0][0][0], bn0,       0,  K, tid);
    stage_half(Bbf, &sB[0][1][0], bn0 + 128, 0,  K, tid);
    stage_half(Bbf, &sB[1][0][0], bn0,       BK, K, tid);
    stage_half(Bbf, &sB[1][1][0], bn0 + 128, BK, K, tid);
    asm volatile("s_waitcnt vmcnt(4)");      // tile0's 8 loads landed
    __builtin_amdgcn_s_barrier();
    // P1's operands (tile0, landed & published above)
    RD_A(aS0, Ab0, 0, Aoff0)
    RD_B(bS0, Bb0, Boff0)

    // ---- main loop: 2 K-tiles per iteration (buf0 = t, buf1 = t+1).
    // Stage ring (R13-exact): A0A1(t+1)@P1P2, B0B1A0A1(t+2)@P4-P7, B0B1(t+3)@P8.
    // vmcnt(2)@P4 / vmcnt(4)@P8 precede the barrier that publishes the buffer;
    // the reads of that buffer are in the SAME phase's post-region (after it).
    for (int t = 0; t < NT; t += 2) {
        int u2 = t + 2; if (u2 >= NT) u2 -= NT;   // wrap stages = harmless dummies
        int u3 = t + 3; if (u3 >= NT) u3 -= NT;
        const int k1 = (t + 1) * BK, k2 = u2 * BK, k3 = u3 * BK;

        // P1: MFMA tile t, kk=0, q0; read P2 ops
        PH(0, aS0, bS0,
           RD_A(aS1, Ab0, 1, Aoff0),
           stage_half(Abf, &sA[1][0][0], bm0, k1, K, tid);, )

        // P2: q1; read P3 ops
        PH(1, aS1, bS0,
           RD_A(aS0, Ab0, 0, Aoff1) RD_B(bS1, Bb0, Boff1),
           stage_half(Abf, &sA[1][1][0], bm0 + 128, k1, K, tid);, )

        // P3: kk=32, q0; read P4 ops (no stage)
        PH(0, aS0, bS1,
           RD_A(aS1, Ab0, 1, Aoff1), , )

        // P4: q1; vmcnt(2) publishes tile t+1; read P5 ops (buf1) post-barrier
        PH(1, aS1, bS1,
           RD_A(aS0, Ab1, 0, Aoff0) RD_B(bS0, Bb1, Boff0),
           stage_half(Bbf, &sB[0][0][0], bn0, k2, K, tid);,
           asm volatile("s_waitcnt vmcnt(2)");)

        // P5: tile t+1, kk=0, q0; read P6 ops
        PH(0, aS0, bS0,
           RD_A(aS1, Ab1, 1, Aoff0),
           stage_half(Bbf, &sB[0][1][0], bn0 + 128, k2, K, tid);, )

        // P6: q1; read P7 ops
        PH(1, aS1, bS0,
           RD_A(aS0, Ab1, 0, Aoff1) RD_B(bS1, Bb1, Boff1),
           stage_half(Abf, &sA[0][0][0], bm0, k2, K, tid);, )

        // P7: kk=32, q0; read P8 ops
        PH(0, aS0, bS1,
           RD_A(aS1, Ab1, 1, Aoff1),
           stage_half(Abf, &sA[0][1][0], bm0 + 128, k2, K, tid);, )

        // P8: q1; vmcnt(4) publishes tile t+2 (buf0); read next-P1 ops post-bar
        PH(1, aS1, bS1,
           RD_A(aS0, Ab0, 0, Aoff0) RD_B(bS0, Bb0, Boff0),
           stage_half(Bbf, &sB[1][0][0], bn0, k3, K, tid);
           stage_half(Bbf, &sB[1][1][0], bn0 + 128, k3, K, tid);,
           asm volatile("s_waitcnt vmcnt(4)");)
    }

    asm volatile("s_waitcnt vmcnt(0) lgkmcnt(0)" ::: "memory");  // drain

    // ---- epilogue: + bias, final mantissa round, store fp32.
    // C/D layout (verified m89/m91): row = lkg*4 + reg, col = lrow.
#pragma unroll
    for (int ia = 0; ia < 8; ++ia) {
        const int row = bm0 + wm * 128 + ia * 16 + lkg * 4;
#pragma unroll
        for (int j = 0; j < 4; ++j) {
            const int col = bn0 + wn * 64 + j * 16 + lrow;
            const float bv = bias[col];
#pragma unroll
            for (int r = 0; r < 4; ++r)
                out[(size_t)(row + r) * N + col] = round_m10(acc[ia][j][r] + bv);
        }
    }
#undef RD_A
#undef RD_B
#undef PH
}

// Fallback: fused fp32->bf16 128^2 kernel (only for shapes the main path rejects).
__global__ __launch_bounds__(256)
void gemm_fallback(const float* __restrict__ A, const float* __restrict__ B,
                   const float* __restrict__ bias, float* __restrict__ out,
                   int M, int N, int K) {
    __shared__ unsigned short lds_a[128 * 64];
    __shared__ unsigned short lds_b[128 * 64];
    const int tid = threadIdx.x, lane = tid & 63, wave = tid >> 6;
    const int wm = wave >> 1, wn = wave & 1;
    const int bm0 = blockIdx.y * 128, bn0 = blockIdx.x * 128;
    const int lrow = lane & 15, lkg = lane >> 4;
    f32x4 acc[4][4];
    const f32x4 zero = {0.f, 0.f, 0.f, 0.f};
#pragma unroll
    for (int i = 0; i < 4; ++i)
#pragma unroll
        for (int j = 0; j < 4; ++j) acc[i][j] = zero;
    for (int kb = 0; kb < K / 64; ++kb) {
        const int kt = kb * 64;
        const int r0 = tid >> 4, c0 = (tid & 15) << 2;
#pragma unroll
        for (int p = 0; p < 8; ++p) {
            const int r = p * 16 + r0;
            f32x4 va = *(const f32x4*)(A + (size_t)(bm0 + r) * K + kt + c0);
            f32x4 vb = *(const f32x4*)(B + (size_t)(bn0 + r) * K + kt + c0);
            ushort4 ua, ub;
            ua.x = f32_to_bf16(va[0]); ua.y = f32_to_bf16(va[1]);
            ua.z = f32_to_bf16(va[2]); ua.w = f32_to_bf16(va[3]);
            ub.x = f32_to_bf16(vb[0]); ub.y = f32_to_bf16(vb[1]);
            ub.z = f32_to_bf16(vb[2]); ub.w = f32_to_bf16(vb[3]);
            *(ushort4*)(&lds_a[r * 64 + c0]) = ua;
            *(ushort4*)(&lds_b[r * 64 + c0]) = ub;
        }
        __syncthreads();
#pragma unroll
        for (int kk = 0; kk < 64; kk += 32) {
            bf16x8 af[4], bfr[4];
#pragma unroll
            for (int i = 0; i < 4; ++i)
                af[i] = *(const bf16x8*)(&lds_a[(wm * 64 + i * 16 + lrow) * 64 + kk + lkg * 8]);
#pragma unroll
            for (int j = 0; j < 4; ++j)
                bfr[j] = *(const bf16x8*)(&lds_b[(wn * 64 + j * 16 + lrow) * 64 + kk + lkg * 8]);
#pragma unroll
            for (int i = 0; i < 4; ++i)
#pragma unroll
                for (int j = 0; j < 4; ++j)
                    acc[i][j] = __builtin_amdgcn_mfma_f32_16x16x32_bf16(af[i], bfr[j], acc[i][j], 0, 0, 0);
        }
        __syncthreads();
    }
#pragma unroll
    for (int i = 0; i < 4; ++i) {
        const int row0 = bm0 + wm * 64 + i * 16 + lkg * 4;
#pragma unroll
        for (int j = 0; j < 4; ++j) {
            const int col = bn0 + wn * 64 + j * 16 + lrow;
            const float bv = bias[col];
#pragma unroll
            for (int r = 0; r < 4; ++r)
                out[(size_t)(row0 + r) * N + col] = round_m10(acc[i][j][r] + bv);
        }
    }
}

extern "C" void kernel_launch(void* const* d_in, const int* in_sizes, int n_in,
                              void* d_out, int out_size, void* d_ws, size_t ws_size,
                              hipStream_t stream) {
    const float* x    = (const float*)d_in[0];   // [M, K]
    const float* w    = (const float*)d_in[1];   // [N, K]
    const float* bias = (const float*)d_in[2];   // [N]
    float* out = (float*)d_out;                  // [M, N]

    const int N = in_sizes[2];
    const int K = in_sizes[1] / N;
    const int M = in_sizes[0] / K;

    const size_t nx = (size_t)M * K;
    const size_t nw = (size_t)N * K;
    const size_t need = (nx + nw) * sizeof(unsigned short);
    const int NT = K / BK;

    if (ws_size >= need && (M % BMN) == 0 && (N % BMN) == 0 && (K % BK) == 0 &&
        NT >= 4 && (NT % 2) == 0) {
        unsigned short* xb = (unsigned short*)d_ws;
        unsigned short* wb = xb + nx;
        const int cpr = K / 8;
        convert2_f32_bf16_swz<<<2048, 256, 0, stream>>>(
            x, xb, w, wb, (long)(nx / 8), (long)((nx + nw) / 8), cpr);
        dim3 grid(N / BMN, M / BMN);
        gemm8p<<<grid, NTHREADS, 0, stream>>>(xb, wb, bias, out, M, N, K);
    } else {
        dim3 grid(N / 128, M / 128);
        gemm_fallback<<<grid, 256, 0, stream>>>(x, w, bias, out, M, N, K);
    }
}